// Round 20
// baseline (116.662 us; speedup 1.0000x reference)
//
#include <hip/hip_runtime.h>
#include <hip/hip_bf16.h>

typedef __bf16 bf16x8 __attribute__((ext_vector_type(8)));
typedef float f32x4 __attribute__((ext_vector_type(4)));
typedef short short8 __attribute__((ext_vector_type(8)));

#define MFMA16(a, b, c) __builtin_amdgcn_mfma_f32_16x16x32_bf16((a), (b), (c), 0, 0, 0)

static constexpr int S = 2048;
static constexpr int D = 512;
static constexpr int HD = 64;
static constexpr int KBLK = 64;
// q scale: 1/sqrt(HD) * log2(e), so softmax can use exp2
#define QSCALE 0.18033688011112042f

typedef __attribute__((address_space(1))) const unsigned int gu32;
typedef __attribute__((address_space(3))) unsigned int lu32;

__device__ __forceinline__ void gll16(const void* g, void* l) {
  __builtin_amdgcn_global_load_lds((gu32*)g, (lu32*)l, 16, 0, 0);
}

__device__ __forceinline__ unsigned short f2b(float f) {
  return __builtin_bit_cast(unsigned short, __float2bfloat16(f));
}
__device__ __forceinline__ float b2f(unsigned short u) {
  return __builtin_bit_cast(float, (unsigned)u << 16);
}

// ------------- merged prep: [0,4096) cast_x | [4096,6144) maskbits | [6144,6400) wtrans4 -------------
// q/k weight columns are PERMUTED: stored pos (p*2+f)*64 + hi*32 + c holds original output dim
// (p+4*hi)*64 + f*32 + c. Rotate-half pairs (d, d+-256) then land at pos ^ 32 -- same GEMM wave,
// same lane (acc[i][j] <-> acc[i][j+2]) -- so RoPE is applied in gemm2's epilogue, lane-locally.
__global__ void prep_kernel(const float* __restrict__ x, unsigned short* __restrict__ xb,
                            const int* __restrict__ m, unsigned long long* __restrict__ bits,
                            const float* __restrict__ wq, const float* __restrict__ wk,
                            const float* __restrict__ wv, const float* __restrict__ wo,
                            unsigned short* __restrict__ wqkvT, unsigned short* __restrict__ woT) {
  __shared__ float t[64][65];
  const int blk = blockIdx.x;
  const int tid = threadIdx.x;
  if (blk < 4096) {
    // cast x (f32 -> bf16), 4 elems/thread
    int idx = blk * 256 + tid;
    float4 v = ((const float4*)x)[idx];
    ushort4 o;
    o.x = f2b(v.x); o.y = f2b(v.y); o.z = f2b(v.z); o.w = f2b(v.w);
    ((ushort4*)xb)[idx] = o;
  } else if (blk < 6144) {
    // mask (int32 0/1) -> bitmask, grid-stride over 16.7M elems
    const int stride = 2048 * 256;
    const int lane0 = (tid & 63) == 0;
    for (int gid = (blk - 4096) * 256 + tid; gid < 4 * 2048 * 2048; gid += stride) {
      unsigned long long w = __ballot(m[gid] != 0);
      if (lane0) bits[gid >> 6] = w;
    }
  } else {
    // tiled transpose+cast of the 4 weight matrices (q/k with column permutation)
    const int tt = blk - 6144;          // 0..255
    const int z = tt >> 6, r = tt & 63;
    const float* w = (z == 0) ? wq : (z == 1) ? wk : (z == 2) ? wv : wo;
    unsigned short* dst = (z < 3) ? wqkvT + (size_t)z * 512 * 512 : woT;
    const int i0 = (r & 7) * 64, o0 = (r >> 3) * 64;
    for (int it = 0; it < 16; ++it) {
      int idx = it * 256 + tid;
      int ii = idx >> 6, oo = idx & 63;
      t[oo][ii] = w[(size_t)(i0 + ii) * 512 + o0 + oo];
    }
    __syncthreads();
    for (int it = 0; it < 16; ++it) {
      int idx = it * 256 + tid;
      int oo = idx >> 6, ii = idx & 63;
      int o = o0 + oo, od;
      if (z < 2) {
        const int hh = o >> 6, ff = (o >> 5) & 1, cc = o & 31;
        od = ((hh & 3) * 2 + ff) * 64 + ((hh >> 2) << 5) + cc;
      } else {
        od = o;
      }
      dst[(size_t)od * 512 + i0 + ii] = f2b(t[oo][ii]);
    }
  }
}

// ------------- proj GEMM: [q|k|v] = x * wqkvT^T, gll16-staged dbuf, 128x128 tile BK=32 -------------
// q/k epilogue: in-register RoPE (permuted pair at acc[i][j]<->acc[i][j+2]) + scatter to [B,H,S,HD]
// final layout (q pre-scaled by QSCALE). v epilogue: LDS transpose -> V^T [B,H,HD,S].
__global__ __launch_bounds__(256)
void gemm2(const unsigned short* __restrict__ A, const unsigned short* __restrict__ Bt,
           const float* __restrict__ cose, const float* __restrict__ sine,
           unsigned short* __restrict__ qd, unsigned short* __restrict__ kd,
           unsigned short* __restrict__ vtd) {
  __shared__ alignas(16) unsigned char smem[36864];  // 32KB staging | 36KB V-transpose (union)
  unsigned short (*lds)[2][4096] = (unsigned short (*)[2][4096])smem;
  const int tid = threadIdx.x;
  const int lane = tid & 63, l15 = lane & 15, lg = lane >> 4;
  const int wave = tid >> 6;
  const int K = 512;
  const int m0 = blockIdx.x * 128, n0 = blockIdx.y * 128;
  const int wm = (wave >> 1) * 64, wn = (wave & 1) * 64;
  const int wbase = wave * 512;  // ushort units; gll16 dest is wave-uniform base + lane*16B
  const int grow = tid >> 2, gcol = (tid & 3) * 8;
  f32x4 acc[4][4] = {};

#define GSTAGE(sb, kk)                                                              \
  do {                                                                              \
    gll16(&A[(size_t)(m0 + grow) * K + (kk) + gcol], &lds[sb][0][wbase]);           \
    gll16(&A[(size_t)(m0 + 64 + grow) * K + (kk) + gcol], &lds[sb][0][2048 + wbase]);\
    gll16(&Bt[(size_t)(n0 + grow) * K + (kk) + gcol], &lds[sb][1][wbase]);          \
    gll16(&Bt[(size_t)(n0 + 64 + grow) * K + (kk) + gcol], &lds[sb][1][2048 + wbase]);\
  } while (0)

  GSTAGE(0, 0);
  asm volatile("s_waitcnt vmcnt(0)" ::: "memory");
  __syncthreads();
  for (int t = 0; t < 16; ++t) {
    const int cur = t & 1;
    if (t + 1 < 16) GSTAGE(cur ^ 1, (t + 1) * 32);
    bf16x8 af[4], bfr[4];
#pragma unroll
    for (int i = 0; i < 4; ++i) {
      af[i]  = *(const bf16x8*)&lds[cur][0][(wm + i * 16 + l15) * 32 + lg * 8];
      bfr[i] = *(const bf16x8*)&lds[cur][1][(wn + i * 16 + l15) * 32 + lg * 8];
    }
    __builtin_amdgcn_s_setprio(1);
#pragma unroll
    for (int i = 0; i < 4; ++i)
#pragma unroll
      for (int j = 0; j < 4; ++j)
        acc[i][j] = MFMA16(af[i], bfr[j], acc[i][j]);
    __builtin_amdgcn_s_setprio(0);
    asm volatile("s_waitcnt vmcnt(0)" ::: "memory");
    __syncthreads();
  }
#undef GSTAGE

  const int sel = n0 >> 9;  // block never crosses a 512 boundary
  const int nb = (n0 & 511) + wn;
  const int b0 = m0 >> 11;
  if (sel < 2) {
    // ---- in-register RoPE + scatter to final per-head layout ----
    unsigned short* dst = (sel == 0) ? qd : kd;
    const float qs = (sel == 0) ? QSCALE : 1.f;
    const int g = nb >> 6, p = g >> 1, f = g & 1;
    const int sbase = (m0 & 2047) + wm;
#pragma unroll
    for (int i = 0; i < 4; ++i)
#pragma unroll
      for (int jl = 0; jl < 2; ++jl) {
        const int c = jl * 16 + l15;
        const int dtr = p * 64 + f * 32 + c;   // trig col (d < 256 member of the pair)
        const int hd = f * 32 + c;
#pragma unroll
        for (int r = 0; r < 4; ++r) {
          const int s = sbase + i * 16 + lg * 4 + r;
          const float cs = cose[(size_t)s * 512 + dtr];
          const float sn = sine[(size_t)s * 512 + dtr];
          const float lo = acc[i][jl][r], hi = acc[i][jl + 2][r];
          dst[(((size_t)(b0 * 8) + p) * 2048 + s) * 64 + hd] = f2b((lo * cs - hi * sn) * qs);
          dst[(((size_t)(b0 * 8) + p + 4) * 2048 + s) * 64 + hd] = f2b((hi * cs + lo * sn) * qs);
        }
      }
  } else {
    // V transposed via per-wave LDS transpose. tb: 64 rows (nn) x 72 ushorts.
    unsigned short* tb = (unsigned short*)smem + wave * 4608;
#pragma unroll
    for (int i = 0; i < 4; ++i)
#pragma unroll
      for (int j = 0; j < 4; ++j) {
        ushort4 pk;
        pk.x = f2b(acc[i][j][0]); pk.y = f2b(acc[i][j][1]);
        pk.z = f2b(acc[i][j][2]); pk.w = f2b(acc[i][j][3]);
        *(ushort4*)&tb[(j * 16 + l15) * 72 + i * 16 + lg * 4] = pk;
      }
    const int s0 = (m0 & 2047) + wm;
    const int g = lane >> 3, c = lane & 7;
#pragma unroll
    for (int rr = 0; rr < 8; ++rr) {
      const int row = rr * 8 + g;
      const int nng = nb + row;
      uint4 v = *(const uint4*)&tb[row * 72 + c * 8];
      *(uint4*)&vtd[(((size_t)(b0 * 8) + (nng >> 6)) * 64 + (nng & 63)) * 2048 + s0 + c * 8] = v;
    }
  }
}

// ------------- flash attention: 2 q-chunks/wave, split-K=4 (grid 1024 = 4 blocks/CU) -------------
// grid 1024 = 8 xcd x 4 bh x 4 kh x 8 qchunk; 512 thr, 8 waves; each block does 8 k-tiles.
// Per-wave structure (proven r14/r16): q-rows [q0,q0+16) and [q0+128,q0+144); kf/vf loaded once,
// shared by both chunks. 33.3KB LDS x 4 blocks/CU = 133KB -> up to 32 waves/CU (was 2 blocks).
// BF16 partials (4 buffers). P in-register via pi; raw v_exp (FTZ: bias -300 -> 0); no max.
__global__ __launch_bounds__(512)
void flash_kernel(const unsigned short* __restrict__ qb, const unsigned short* __restrict__ kb,
                  const unsigned short* __restrict__ vtb, const unsigned long long* __restrict__ mbits,
                  unsigned short* __restrict__ op0, unsigned short* __restrict__ op1,
                  unsigned short* __restrict__ op2, unsigned short* __restrict__ op3,
                  float* __restrict__ ls0, float* __restrict__ ls1,
                  float* __restrict__ ls2, float* __restrict__ ls3) {
  __shared__ alignas(16) unsigned short kv[2][2][4096];   // [stage][K|V][64x64 bf16], src-swizzled
  __shared__ alignas(16) f32x4 btab[16];                  // nibble -> bias4 (0 or -300 per bit)
  const int tid = threadIdx.x;
  const int wave = tid >> 6, lane = tid & 63;
  const int l15 = lane & 15, lg = lane >> 4;
  const int swz = (l15 & 7) << 4;
  const int wgid = blockIdx.x;
  const int slot = wgid >> 3;                   // 0..127
  const int bh = (wgid & 7) * 4 + (slot & 3);
  const int rest = slot >> 2;                   // 0..31
  const int kh = rest & 3;                      // K quarter
  const int q0 = (rest >> 2) * 256 + wave * 16; // chunk A; chunk B at +128
  const int b = bh >> 3, h = bh & 7;
  const int kbase = kh * 512;
  const unsigned short* Q = qb + ((size_t)bh * S + q0) * HD;
  const unsigned short* Kp = kb + (size_t)bh * S * HD;
  const unsigned short* Vt = vtb + (size_t)bh * HD * S;
  const unsigned long long* MrowA = mbits + ((size_t)b * S + q0 + l15) * (S / 64) + kh * 8;
  const unsigned long long* MrowB = MrowA + (size_t)128 * (S / 64);
  unsigned short* opart = (kh == 0) ? op0 : (kh == 1) ? op1 : (kh == 2) ? op2 : op3;
  float* lsum = (kh == 0) ? ls0 : (kh == 1) ? ls1 : (kh == 2) ? ls2 : ls3;

  const int srow = tid >> 3;
  const int scol = ((tid & 7) ^ (srow & 7)) * 8;
  const int ksrow = ((srow & 15) >> 2) * 8 + ((srow >> 4) & 1) * 4 + (srow & 3) + (srow >> 5) * 32;
  const int wbase = wave * 512;  // ushort units (wave-uniform)

  if (tid < 16) {
    f32x4 e;
    e[0] = (tid & 1) ? 0.f : -300.f;
    e[1] = (tid & 2) ? 0.f : -300.f;
    e[2] = (tid & 4) ? 0.f : -300.f;
    e[3] = (tid & 8) ? 0.f : -300.f;
    btab[tid] = e;
  }

  bf16x8 qf0a = *(const bf16x8*)&Q[l15 * HD + lg * 8];
  bf16x8 qf1a = *(const bf16x8*)&Q[l15 * HD + 32 + lg * 8];
  bf16x8 qf0b = *(const bf16x8*)&Q[(128 + l15) * HD + lg * 8];
  bf16x8 qf1b = *(const bf16x8*)&Q[(128 + l15) * HD + 32 + lg * 8];
  f32x4 oa[4] = {}, ob[4] = {};
  float lpa = 0.f, lpb = 0.f;
  const int lgs8 = lg * 8;

  unsigned long long wAa = MrowA[0], wAb = MrowB[0];
  gll16(&Kp[(size_t)(kbase + ksrow) * HD + scol], &kv[0][0][wbase]);
  gll16(&Vt[(size_t)srow * S + kbase + scol], &kv[0][1][wbase]);
  asm volatile("s_waitcnt vmcnt(0) lgkmcnt(0)" ::: "memory");
  __syncthreads();

  for (int t = 0; t < 8; ++t) {
    const int cur = t & 1;
    unsigned long long wBa = 0, wBb = 0;
    if (t + 1 < 8) {
      const int kn = kbase + (t + 1) * KBLK;
      gll16(&Kp[(size_t)(kn + ksrow) * HD + scol], &kv[cur ^ 1][0][wbase]);
      gll16(&Vt[(size_t)srow * S + kn + scol], &kv[cur ^ 1][1][wbase]);
      wBa = MrowA[t + 1];
      wBb = MrowB[t + 1];
    }
    const char* kbp = (const char*)&kv[cur][0][0];
    const char* vbp = (const char*)&kv[cur][1][0];

    // ---- per-n: QK (shared kf) -> folded softmax -> pf halves; scA/scB die each n ----
    bf16x8 pf0a, pf1a, pf0b, pf1b;
#pragma unroll
    for (int n = 0; n < 4; ++n) {
      const int cb = (n * 16 + l15) * 128 + ((lg * 16) ^ swz);
      bf16x8 kf0 = *(const bf16x8*)(kbp + cb);
      bf16x8 kf1 = *(const bf16x8*)(kbp + (cb ^ 64));
      f32x4 scA = {}, scB = {};
      __builtin_amdgcn_s_setprio(1);
      scA = MFMA16(kf0, qf0a, scA);  // swapped: lane owns q=l15, k=pi(n*16+lg*4+r)
      scA = MFMA16(kf1, qf1a, scA);
      scB = MFMA16(kf0, qf0b, scB);
      scB = MFMA16(kf1, qf1b, scB);
      __builtin_amdgcn_s_setprio(0);
      const int sh = (n == 0) ? 0 : (n == 1) ? 4 : (n == 2) ? 32 : 36;
      const f32x4 ba = btab[(unsigned)(wAa >> (lgs8 + sh)) & 15u];
      const f32x4 bb = btab[(unsigned)(wAb >> (lgs8 + sh)) & 15u];
      f32x4 pa, pb;
#pragma unroll
      for (int r = 0; r < 4; ++r) {
        pa[r] = __builtin_amdgcn_exp2f(scA[r] + ba[r]);
        pb[r] = __builtin_amdgcn_exp2f(scB[r] + bb[r]);
      }
      lpa += (pa[0] + pa[1]) + (pa[2] + pa[3]);
      lpb += (pb[0] + pb[1]) + (pb[2] + pb[3]);
      bf16x8& dsta = (n < 2) ? pf0a : pf1a;
      bf16x8& dstb = (n < 2) ? pf0b : pf1b;
      const int jo = (n & 1) * 4;
#pragma unroll
      for (int j = 0; j < 4; ++j) {
        dsta[jo + j] = (__bf16)pa[j];
        dstb[jo + j] = (__bf16)pb[j];
      }
    }

    // ---- PV (shared vf): oa/ob += P x V ----
    __builtin_amdgcn_s_setprio(1);
#pragma unroll
    for (int n = 0; n < 4; ++n) {
      const int cb = (n * 16 + l15) * 128 + ((lg * 16) ^ swz);
      bf16x8 vf0 = *(const bf16x8*)(vbp + cb);
      bf16x8 vf1 = *(const bf16x8*)(vbp + (cb ^ 64));
      oa[n] = MFMA16(pf0a, vf0, oa[n]);
      oa[n] = MFMA16(pf1a, vf1, oa[n]);
      ob[n] = MFMA16(pf0b, vf0, ob[n]);
      ob[n] = MFMA16(pf1b, vf1, ob[n]);
    }
    __builtin_amdgcn_s_setprio(0);

    asm volatile("s_waitcnt vmcnt(0)" ::: "memory");  // next tile landed
    __syncthreads();
    wAa = wBa;
    wAb = wBb;
  }

  lpa += __shfl_xor(lpa, 16);
  lpa += __shfl_xor(lpa, 32);
  lpb += __shfl_xor(lpb, 16);
  lpb += __shfl_xor(lpb, 32);
  if (lg == 0) {
    lsum[(size_t)bh * S + q0 + l15] = lpa;
    lsum[(size_t)bh * S + q0 + 128 + l15] = lpb;
  }
#pragma unroll
  for (int r = 0; r < 4; ++r)
#pragma unroll
    for (int n = 0; n < 4; ++n) {
      opart[((size_t)(b * S + q0 + lg * 4 + r)) * D + h * HD + n * 16 + l15] = f2b(oa[n][r]);
      opart[((size_t)(b * S + q0 + 128 + lg * 4 + r)) * D + h * HD + n * 16 + l15] = f2b(ob[n][r]);
    }
}

// ------------- fused out GEMM: A = (op0+op1+op2+op3)*inv[row][head] (bf16 partials) -------------
__global__ __launch_bounds__(256)
void gemm_fused(const unsigned short* __restrict__ op0, const unsigned short* __restrict__ op1,
                const unsigned short* __restrict__ op2, const unsigned short* __restrict__ op3,
                const float* __restrict__ ls0, const float* __restrict__ ls1,
                const float* __restrict__ ls2, const float* __restrict__ ls3,
                const unsigned short* __restrict__ Bt, float* __restrict__ C) {
  __shared__ alignas(16) unsigned short ldsA[2][2048];  // [stage][64*32]
  __shared__ alignas(16) unsigned short ldsB[2][4096];  // [stage][128*32]
  __shared__ float invt[512];                           // [row64][head8]
  const int tid = threadIdx.x;
  const int lane = tid & 63, l15 = lane & 15, lg = lane >> 4;
  const int wave = tid >> 6;
  const int m0 = blockIdx.x * 64, n0 = blockIdx.y * 128;
  const int wm = (wave >> 1) * 32, wn = (wave & 1) * 64;
  const int wbase = wave * 512;
  const int grow = tid >> 2, gcol = (tid & 3) * 8;
  const size_t abase = (size_t)(m0 + (tid >> 2)) * 512 + (tid & 3) * 8;
  f32x4 acc[2][4] = {};

  for (int e = tid; e < 512; e += 256) {
    const int row = e >> 3, hh = e & 7;
    const int m = m0 + row;
    const size_t li = ((size_t)((m >> 11) * 8 + hh)) * 2048 + (m & 2047);
    const float l = ls0[li] + ls1[li] + ls2[li] + ls3[li];
    invt[e] = (l > 0.f) ? 1.f / l : 0.f;
  }

#define BSTAGE(sb, kk)                                                               \
  do {                                                                               \
    gll16(&Bt[(size_t)(n0 + grow) * 512 + (kk) + gcol], &ldsB[sb][wbase]);           \
    gll16(&Bt[(size_t)(n0 + 64 + grow) * 512 + (kk) + gcol], &ldsB[sb][2048 + wbase]);\
  } while (0)

  short8 a8, p8, c8, d8;
#define ALOAD(kk)                                          \
  do {                                                     \
    a8 = *(const short8*)&op0[abase + (kk)];               \
    p8 = *(const short8*)&op1[abase + (kk)];               \
    c8 = *(const short8*)&op2[abase + (kk)];               \
    d8 = *(const short8*)&op3[abase + (kk)];               \
  } while (0)

#define AWRITE(sb, kk)                                                        \
  do {                                                                        \
    const float inv = invt[((tid >> 2) << 3) | ((kk) >> 6)];                  \
    short8 pk;                                                                \
    _Pragma("unroll")                                                         \
    for (int e = 0; e < 8; ++e) {                                             \
      const float s = (b2f((unsigned short)a8[e]) + b2f((unsigned short)p8[e])) + \
                      (b2f((unsigned short)c8[e]) + b2f((unsigned short)d8[e]));  \
      pk[e] = (short)f2b(s * inv);                                            \
    }                                                                         \
    *(short8*)&ldsA[sb][(tid >> 2) * 32 + (tid & 3) * 8] = pk;                \
  } while (0)

  ALOAD(0);
  BSTAGE(0, 0);
  __syncthreads();          // invt visible; drains A loads + B gll16
  AWRITE(0, 0);
  __syncthreads();          // A(0) visible

  for (int t = 0; t < 16; ++t) {
    const int cur = t & 1;
    const bool have = (t + 1 < 16);
    if (have) { ALOAD((t + 1) * 32); BSTAGE(cur ^ 1, (t + 1) * 32); }
    bf16x8 af[2], bfr[4];
#pragma unroll
    for (int i = 0; i < 2; ++i)
      af[i] = *(const bf16x8*)&ldsA[cur][(wm + i * 16 + l15) * 32 + lg * 8];
#pragma unroll
    for (int j = 0; j < 4; ++j)
      bfr[j] = *(const bf16x8*)&ldsB[cur][(wn + j * 16 + l15) * 32 + lg * 8];
    __builtin_amdgcn_s_setprio(1);
#pragma unroll
    for (int i = 0; i < 2; ++i)
#pragma unroll
      for (int j = 0; j < 4; ++j)
        acc[i][j] = MFMA16(af[i], bfr[j], acc[i][j]);
    __builtin_amdgcn_s_setprio(0);
    asm volatile("s_waitcnt vmcnt(0)" ::: "memory");
    __syncthreads();
    if (have) AWRITE(cur ^ 1, (t + 1) * 32);
    __syncthreads();
  }
#undef BSTAGE
#undef ALOAD
#undef AWRITE

#pragma unroll
  for (int i = 0; i < 2; ++i)
#pragma unroll
    for (int j = 0; j < 4; ++j)
#pragma unroll
      for (int r = 0; r < 4; ++r)
        C[(size_t)(m0 + wm + i * 16 + lg * 4 + r) * 512 + (n0 + wn + j * 16 + l15)] = acc[i][j][r];
}

extern "C" void kernel_launch(void* const* d_in, const int* in_sizes, int n_in,
                              void* d_out, int out_size, void* d_ws, size_t ws_size,
                              hipStream_t stream) {
  const float* x = (const float*)d_in[0];
  const float* cose = (const float*)d_in[1];
  const float* sine = (const float*)d_in[2];
  const int* mask = (const int*)d_in[3];
  const float* wq = (const float*)d_in[4];
  const float* wk = (const float*)d_in[5];
  const float* wv = (const float*)d_in[6];
  const float* wo = (const float*)d_in[7];
  float* out = (float*)d_out;
  char* ws = (char*)d_ws;

  // workspace layout (bytes)
  unsigned short* xb    = (unsigned short*)(ws);                 //  8,388,608  x bf16 [8192][512]
  unsigned short* wqkvT = (unsigned short*)(ws + 8388608);       //  1,572,864  [1536][512]
  unsigned short* woT   = (unsigned short*)(ws + 9961472);       //    524,288  [512][512]
  unsigned short* op0   = (unsigned short*)(ws + 10485760);      //  8,388,608  bf16 partials kh=0
  unsigned short* op1   = (unsigned short*)(ws + 18874368);      //  8,388,608  kh=1
  unsigned short* op2   = (unsigned short*)(ws + 27262976);      //  8,388,608  kh=2
  unsigned short* qbh   = (unsigned short*)(ws + 35651584);      //  8,388,608  roped q [B,H,S,HD]
  unsigned short* kbh   = (unsigned short*)(ws + 44040192);      //  8,388,608  roped k
  unsigned short* vtb   = (unsigned short*)(ws + 52428800);      //  8,388,608  V^T [B,H,HD,S]
  unsigned long long* mbits = (unsigned long long*)(ws + 60817408);  // 2,097,152
  unsigned short* op3   = (unsigned short*)(ws + 62914560);      //  8,388,608  kh=3
  float* ls0 = (float*)(ws + 71303168);   //    262,144
  float* ls1 = (float*)(ws + 71565312);   //    262,144
  float* ls2 = (float*)(ws + 71827456);   //    262,144
  float* ls3 = (float*)(ws + 72089600);   //    262,144  (ends 72,351,744)

  prep_kernel<<<6400, 256, 0, stream>>>(x, xb, mask, mbits, wq, wk, wv, wo, wqkvT, woT);
  gemm2<<<dim3(64, 12), 256, 0, stream>>>(xb, wqkvT, cose, sine, qbh, kbh, vtb);
  flash_kernel<<<1024, 512, 0, stream>>>(qbh, kbh, vtb, mbits, op0, op1, op2, op3,
                                         ls0, ls1, ls2, ls3);
  gemm_fused<<<dim3(128, 4), 256, 0, stream>>>(op0, op1, op2, op3, ls0, ls1, ls2, ls3, woT, out);
}

// Round 21
// 107.667 us; speedup vs baseline: 1.0835x; 1.0835x over previous
//
#include <hip/hip_runtime.h>
#include <hip/hip_bf16.h>

typedef __bf16 bf16x8 __attribute__((ext_vector_type(8)));
typedef float f32x4 __attribute__((ext_vector_type(4)));
typedef short short8 __attribute__((ext_vector_type(8)));

#define MFMA16(a, b, c) __builtin_amdgcn_mfma_f32_16x16x32_bf16((a), (b), (c), 0, 0, 0)

static constexpr int S = 2048;
static constexpr int D = 512;
static constexpr int HD = 64;
static constexpr int KBLK = 64;
// q scale: 1/sqrt(HD) * log2(e), so softmax can use exp2
#define QSCALE 0.18033688011112042f

typedef __attribute__((address_space(1))) const unsigned int gu32;
typedef __attribute__((address_space(3))) unsigned int lu32;

__device__ __forceinline__ void gll16(const void* g, void* l) {
  __builtin_amdgcn_global_load_lds((gu32*)g, (lu32*)l, 16, 0, 0);
}

__device__ __forceinline__ unsigned short f2b(float f) {
  return __builtin_bit_cast(unsigned short, __float2bfloat16(f));
}
__device__ __forceinline__ float b2f(unsigned short u) {
  return __builtin_bit_cast(float, (unsigned)u << 16);
}

// ------------- merged prep: [0,4096) cast_x | [4096,6144) maskbits | [6144,6400) wtrans4 -------------
// q/k weight columns are PERMUTED: stored pos (p*2+f)*64 + hi*32 + c holds original output dim
// (p+4*hi)*64 + f*32 + c. Rotate-half pairs (d, d+-256) then land at pos ^ 32 -- same GEMM wave,
// same lane (acc[i][j] <-> acc[i][j+2]) -- so RoPE is applied in gemm2's epilogue, lane-locally.
__global__ void prep_kernel(const float* __restrict__ x, unsigned short* __restrict__ xb,
                            const int* __restrict__ m, unsigned long long* __restrict__ bits,
                            const float* __restrict__ wq, const float* __restrict__ wk,
                            const float* __restrict__ wv, const float* __restrict__ wo,
                            unsigned short* __restrict__ wqkvT, unsigned short* __restrict__ woT) {
  __shared__ float t[64][65];
  const int blk = blockIdx.x;
  const int tid = threadIdx.x;
  if (blk < 4096) {
    // cast x (f32 -> bf16), 4 elems/thread
    int idx = blk * 256 + tid;
    float4 v = ((const float4*)x)[idx];
    ushort4 o;
    o.x = f2b(v.x); o.y = f2b(v.y); o.z = f2b(v.z); o.w = f2b(v.w);
    ((ushort4*)xb)[idx] = o;
  } else if (blk < 6144) {
    // mask (int32 0/1) -> bitmask, grid-stride over 16.7M elems
    const int stride = 2048 * 256;
    const int lane0 = (tid & 63) == 0;
    for (int gid = (blk - 4096) * 256 + tid; gid < 4 * 2048 * 2048; gid += stride) {
      unsigned long long w = __ballot(m[gid] != 0);
      if (lane0) bits[gid >> 6] = w;
    }
  } else {
    // tiled transpose+cast of the 4 weight matrices (q/k with column permutation)
    const int tt = blk - 6144;          // 0..255
    const int z = tt >> 6, r = tt & 63;
    const float* w = (z == 0) ? wq : (z == 1) ? wk : (z == 2) ? wv : wo;
    unsigned short* dst = (z < 3) ? wqkvT + (size_t)z * 512 * 512 : woT;
    const int i0 = (r & 7) * 64, o0 = (r >> 3) * 64;
    for (int it = 0; it < 16; ++it) {
      int idx = it * 256 + tid;
      int ii = idx >> 6, oo = idx & 63;
      t[oo][ii] = w[(size_t)(i0 + ii) * 512 + o0 + oo];
    }
    __syncthreads();
    for (int it = 0; it < 16; ++it) {
      int idx = it * 256 + tid;
      int oo = idx >> 6, ii = idx & 63;
      int o = o0 + oo, od;
      if (z < 2) {
        const int hh = o >> 6, ff = (o >> 5) & 1, cc = o & 31;
        od = ((hh & 3) * 2 + ff) * 64 + ((hh >> 2) << 5) + cc;
      } else {
        od = o;
      }
      dst[(size_t)od * 512 + i0 + ii] = f2b(t[oo][ii]);
    }
  }
}

// ------------- proj GEMM: [q|k|v] = x * wqkvT^T, gll16-staged dbuf, 128x128 tile BK=32 -------------
// q/k epilogue: in-register RoPE (permuted pair at acc[i][j]<->acc[i][j+2]) + scatter to [B,H,S,HD]
// final layout (q pre-scaled by QSCALE). v epilogue: LDS transpose -> V^T [B,H,HD,S].
__global__ __launch_bounds__(256)
void gemm2(const unsigned short* __restrict__ A, const unsigned short* __restrict__ Bt,
           const float* __restrict__ cose, const float* __restrict__ sine,
           unsigned short* __restrict__ qd, unsigned short* __restrict__ kd,
           unsigned short* __restrict__ vtd) {
  __shared__ alignas(16) unsigned char smem[36864];  // 32KB staging | 36KB V-transpose (union)
  unsigned short (*lds)[2][4096] = (unsigned short (*)[2][4096])smem;
  const int tid = threadIdx.x;
  const int lane = tid & 63, l15 = lane & 15, lg = lane >> 4;
  const int wave = tid >> 6;
  const int K = 512;
  const int m0 = blockIdx.x * 128, n0 = blockIdx.y * 128;
  const int wm = (wave >> 1) * 64, wn = (wave & 1) * 64;
  const int wbase = wave * 512;  // ushort units; gll16 dest is wave-uniform base + lane*16B
  const int grow = tid >> 2, gcol = (tid & 3) * 8;
  f32x4 acc[4][4] = {};

#define GSTAGE(sb, kk)                                                              \
  do {                                                                              \
    gll16(&A[(size_t)(m0 + grow) * K + (kk) + gcol], &lds[sb][0][wbase]);           \
    gll16(&A[(size_t)(m0 + 64 + grow) * K + (kk) + gcol], &lds[sb][0][2048 + wbase]);\
    gll16(&Bt[(size_t)(n0 + grow) * K + (kk) + gcol], &lds[sb][1][wbase]);          \
    gll16(&Bt[(size_t)(n0 + 64 + grow) * K + (kk) + gcol], &lds[sb][1][2048 + wbase]);\
  } while (0)

  GSTAGE(0, 0);
  asm volatile("s_waitcnt vmcnt(0)" ::: "memory");
  __syncthreads();
  for (int t = 0; t < 16; ++t) {
    const int cur = t & 1;
    if (t + 1 < 16) GSTAGE(cur ^ 1, (t + 1) * 32);
    bf16x8 af[4], bfr[4];
#pragma unroll
    for (int i = 0; i < 4; ++i) {
      af[i]  = *(const bf16x8*)&lds[cur][0][(wm + i * 16 + l15) * 32 + lg * 8];
      bfr[i] = *(const bf16x8*)&lds[cur][1][(wn + i * 16 + l15) * 32 + lg * 8];
    }
    __builtin_amdgcn_s_setprio(1);
#pragma unroll
    for (int i = 0; i < 4; ++i)
#pragma unroll
      for (int j = 0; j < 4; ++j)
        acc[i][j] = MFMA16(af[i], bfr[j], acc[i][j]);
    __builtin_amdgcn_s_setprio(0);
    asm volatile("s_waitcnt vmcnt(0)" ::: "memory");
    __syncthreads();
  }
#undef GSTAGE

  const int sel = n0 >> 9;  // block never crosses a 512 boundary
  const int nb = (n0 & 511) + wn;
  const int b0 = m0 >> 11;
  if (sel < 2) {
    // ---- in-register RoPE + scatter to final per-head layout ----
    unsigned short* dst = (sel == 0) ? qd : kd;
    const float qs = (sel == 0) ? QSCALE : 1.f;
    const int g = nb >> 6, p = g >> 1, f = g & 1;
    const int sbase = (m0 & 2047) + wm;
#pragma unroll
    for (int i = 0; i < 4; ++i)
#pragma unroll
      for (int jl = 0; jl < 2; ++jl) {
        const int c = jl * 16 + l15;
        const int dtr = p * 64 + f * 32 + c;   // trig col (d < 256 member of the pair)
        const int hd = f * 32 + c;
#pragma unroll
        for (int r = 0; r < 4; ++r) {
          const int s = sbase + i * 16 + lg * 4 + r;
          const float cs = cose[(size_t)s * 512 + dtr];
          const float sn = sine[(size_t)s * 512 + dtr];
          const float lo = acc[i][jl][r], hi = acc[i][jl + 2][r];
          dst[(((size_t)(b0 * 8) + p) * 2048 + s) * 64 + hd] = f2b((lo * cs - hi * sn) * qs);
          dst[(((size_t)(b0 * 8) + p + 4) * 2048 + s) * 64 + hd] = f2b((hi * cs + lo * sn) * qs);
        }
      }
  } else {
    // V transposed via per-wave LDS transpose. tb: 64 rows (nn) x 72 ushorts.
    unsigned short* tb = (unsigned short*)smem + wave * 4608;
#pragma unroll
    for (int i = 0; i < 4; ++i)
#pragma unroll
      for (int j = 0; j < 4; ++j) {
        ushort4 pk;
        pk.x = f2b(acc[i][j][0]); pk.y = f2b(acc[i][j][1]);
        pk.z = f2b(acc[i][j][2]); pk.w = f2b(acc[i][j][3]);
        *(ushort4*)&tb[(j * 16 + l15) * 72 + i * 16 + lg * 4] = pk;
      }
    const int s0 = (m0 & 2047) + wm;
    const int g = lane >> 3, c = lane & 7;
#pragma unroll
    for (int rr = 0; rr < 8; ++rr) {
      const int row = rr * 8 + g;
      const int nng = nb + row;
      uint4 v = *(const uint4*)&tb[row * 72 + c * 8];
      *(uint4*)&vtd[(((size_t)(b0 * 8) + (nng >> 6)) * 64 + (nng & 63)) * 2048 + s0 + c * 8] = v;
    }
  }
}

// ------------- flash attention: 2 q-chunks per wave sharing every K/V LDS read -------------
// grid 512 = 8 xcd x 4 bh x 2 kh x 8 qchunk; 512 thr, 8 waves. Wave handles q-rows
// [q0,q0+16) and [q0+128,q0+144); kf/vf loaded once, used by both chunks' MFMAs. BF16
// partials. P in-register via pi; raw v_exp (FTZ: bias -300 -> exact 0); no running max.
__global__ __launch_bounds__(512)
void flash_kernel(const unsigned short* __restrict__ qb, const unsigned short* __restrict__ kb,
                  const unsigned short* __restrict__ vtb, const unsigned long long* __restrict__ mbits,
                  unsigned short* __restrict__ op0, unsigned short* __restrict__ op1,
                  float* __restrict__ ls0, float* __restrict__ ls1) {
  __shared__ alignas(16) unsigned short kv[2][2][4096];   // [stage][K|V][64x64 bf16], src-swizzled
  __shared__ alignas(16) f32x4 btab[16];                  // nibble -> bias4 (0 or -300 per bit)
  const int tid = threadIdx.x;
  const int wave = tid >> 6, lane = tid & 63;
  const int l15 = lane & 15, lg = lane >> 4;
  const int swz = (l15 & 7) << 4;
  const int wgid = blockIdx.x;
  const int slot = wgid >> 3;                   // 0..63
  const int bh = (wgid & 7) * 4 + (slot & 3);
  const int rest = slot >> 2;                   // 0..15
  const int kh = rest & 1;
  const int q0 = (rest >> 1) * 256 + wave * 16; // chunk A; chunk B at +128
  const int b = bh >> 3, h = bh & 7;
  const int kbase = kh * 1024;
  const unsigned short* Q = qb + ((size_t)bh * S + q0) * HD;
  const unsigned short* Kp = kb + (size_t)bh * S * HD;
  const unsigned short* Vt = vtb + (size_t)bh * HD * S;
  const unsigned long long* MrowA = mbits + ((size_t)b * S + q0 + l15) * (S / 64) + kh * 16;
  const unsigned long long* MrowB = MrowA + (size_t)128 * (S / 64);
  unsigned short* opart = kh ? op1 : op0;
  float* lsum = kh ? ls1 : ls0;

  const int srow = tid >> 3;
  const int scol = ((tid & 7) ^ (srow & 7)) * 8;
  const int ksrow = ((srow & 15) >> 2) * 8 + ((srow >> 4) & 1) * 4 + (srow & 3) + (srow >> 5) * 32;
  const int wbase = wave * 512;  // ushort units (wave-uniform)

  if (tid < 16) {
    f32x4 e;
    e[0] = (tid & 1) ? 0.f : -300.f;
    e[1] = (tid & 2) ? 0.f : -300.f;
    e[2] = (tid & 4) ? 0.f : -300.f;
    e[3] = (tid & 8) ? 0.f : -300.f;
    btab[tid] = e;
  }

  bf16x8 qf0a = *(const bf16x8*)&Q[l15 * HD + lg * 8];
  bf16x8 qf1a = *(const bf16x8*)&Q[l15 * HD + 32 + lg * 8];
  bf16x8 qf0b = *(const bf16x8*)&Q[(128 + l15) * HD + lg * 8];
  bf16x8 qf1b = *(const bf16x8*)&Q[(128 + l15) * HD + 32 + lg * 8];
  f32x4 oa[4] = {}, ob[4] = {};
  float lpa = 0.f, lpb = 0.f;
  const int lgs8 = lg * 8;

  unsigned long long wAa = MrowA[0], wAb = MrowB[0];
  gll16(&Kp[(size_t)(kbase + ksrow) * HD + scol], &kv[0][0][wbase]);
  gll16(&Vt[(size_t)srow * S + kbase + scol], &kv[0][1][wbase]);
  asm volatile("s_waitcnt vmcnt(0) lgkmcnt(0)" ::: "memory");
  __syncthreads();

  for (int t = 0; t < 16; ++t) {
    const int cur = t & 1;
    unsigned long long wBa = 0, wBb = 0;
    if (t + 1 < 16) {
      const int kn = kbase + (t + 1) * KBLK;
      gll16(&Kp[(size_t)(kn + ksrow) * HD + scol], &kv[cur ^ 1][0][wbase]);
      gll16(&Vt[(size_t)srow * S + kn + scol], &kv[cur ^ 1][1][wbase]);
      wBa = MrowA[t + 1];
      wBb = MrowB[t + 1];
    }
    const char* kbp = (const char*)&kv[cur][0][0];
    const char* vbp = (const char*)&kv[cur][1][0];

    // ---- per-n: QK (shared kf) -> folded softmax -> pf halves; scA/scB die each n ----
    bf16x8 pf0a, pf1a, pf0b, pf1b;
#pragma unroll
    for (int n = 0; n < 4; ++n) {
      const int cb = (n * 16 + l15) * 128 + ((lg * 16) ^ swz);
      bf16x8 kf0 = *(const bf16x8*)(kbp + cb);
      bf16x8 kf1 = *(const bf16x8*)(kbp + (cb ^ 64));
      f32x4 scA = {}, scB = {};
      __builtin_amdgcn_s_setprio(1);
      scA = MFMA16(kf0, qf0a, scA);  // swapped: lane owns q=l15, k=pi(n*16+lg*4+r)
      scA = MFMA16(kf1, qf1a, scA);
      scB = MFMA16(kf0, qf0b, scB);
      scB = MFMA16(kf1, qf1b, scB);
      __builtin_amdgcn_s_setprio(0);
      const int sh = (n == 0) ? 0 : (n == 1) ? 4 : (n == 2) ? 32 : 36;
      const f32x4 ba = btab[(unsigned)(wAa >> (lgs8 + sh)) & 15u];
      const f32x4 bb = btab[(unsigned)(wAb >> (lgs8 + sh)) & 15u];
      f32x4 pa, pb;
#pragma unroll
      for (int r = 0; r < 4; ++r) {
        pa[r] = __builtin_amdgcn_exp2f(scA[r] + ba[r]);
        pb[r] = __builtin_amdgcn_exp2f(scB[r] + bb[r]);
      }
      lpa += (pa[0] + pa[1]) + (pa[2] + pa[3]);
      lpb += (pb[0] + pb[1]) + (pb[2] + pb[3]);
      bf16x8& dsta = (n < 2) ? pf0a : pf1a;
      bf16x8& dstb = (n < 2) ? pf0b : pf1b;
      const int jo = (n & 1) * 4;
#pragma unroll
      for (int j = 0; j < 4; ++j) {
        dsta[jo + j] = (__bf16)pa[j];
        dstb[jo + j] = (__bf16)pb[j];
      }
    }

    // ---- PV (shared vf): oa/ob += P x V ----
    __builtin_amdgcn_s_setprio(1);
#pragma unroll
    for (int n = 0; n < 4; ++n) {
      const int cb = (n * 16 + l15) * 128 + ((lg * 16) ^ swz);
      bf16x8 vf0 = *(const bf16x8*)(vbp + cb);
      bf16x8 vf1 = *(const bf16x8*)(vbp + (cb ^ 64));
      oa[n] = MFMA16(pf0a, vf0, oa[n]);
      oa[n] = MFMA16(pf1a, vf1, oa[n]);
      ob[n] = MFMA16(pf0b, vf0, ob[n]);
      ob[n] = MFMA16(pf1b, vf1, ob[n]);
    }
    __builtin_amdgcn_s_setprio(0);

    asm volatile("s_waitcnt vmcnt(0)" ::: "memory");  // next tile landed
    __syncthreads();
    wAa = wBa;
    wAb = wBb;
  }

  lpa += __shfl_xor(lpa, 16);
  lpa += __shfl_xor(lpa, 32);
  lpb += __shfl_xor(lpb, 16);
  lpb += __shfl_xor(lpb, 32);
  if (lg == 0) {
    lsum[(size_t)bh * S + q0 + l15] = lpa;
    lsum[(size_t)bh * S + q0 + 128 + l15] = lpb;
  }
#pragma unroll
  for (int r = 0; r < 4; ++r)
#pragma unroll
    for (int n = 0; n < 4; ++n) {
      opart[((size_t)(b * S + q0 + lg * 4 + r)) * D + h * HD + n * 16 + l15] = f2b(oa[n][r]);
      opart[((size_t)(b * S + q0 + 128 + lg * 4 + r)) * D + h * HD + n * 16 + l15] = f2b(ob[n][r]);
    }
}

// ------------- fused out GEMM: A = (op0+op1)*inv[row][head] (bf16 partials) -------------
__global__ __launch_bounds__(256)
void gemm_fused(const unsigned short* __restrict__ op0, const unsigned short* __restrict__ op1,
                const float* __restrict__ ls0, const float* __restrict__ ls1,
                const unsigned short* __restrict__ Bt, float* __restrict__ C) {
  __shared__ alignas(16) unsigned short ldsA[2][2048];  // [stage][64*32]
  __shared__ alignas(16) unsigned short ldsB[2][4096];  // [stage][128*32]
  __shared__ float invt[512];                           // [row64][head8]
  const int tid = threadIdx.x;
  const int lane = tid & 63, l15 = lane & 15, lg = lane >> 4;
  const int wave = tid >> 6;
  const int m0 = blockIdx.x * 64, n0 = blockIdx.y * 128;
  const int wm = (wave >> 1) * 32, wn = (wave & 1) * 64;
  const int wbase = wave * 512;
  const int grow = tid >> 2, gcol = (tid & 3) * 8;
  const size_t abase = (size_t)(m0 + (tid >> 2)) * 512 + (tid & 3) * 8;
  f32x4 acc[2][4] = {};

  for (int e = tid; e < 512; e += 256) {
    const int row = e >> 3, hh = e & 7;
    const int m = m0 + row;
    const size_t li = ((size_t)((m >> 11) * 8 + hh)) * 2048 + (m & 2047);
    const float l = ls0[li] + ls1[li];
    invt[e] = (l > 0.f) ? 1.f / l : 0.f;
  }

#define BSTAGE(sb, kk)                                                               \
  do {                                                                               \
    gll16(&Bt[(size_t)(n0 + grow) * 512 + (kk) + gcol], &ldsB[sb][wbase]);           \
    gll16(&Bt[(size_t)(n0 + 64 + grow) * 512 + (kk) + gcol], &ldsB[sb][2048 + wbase]);\
  } while (0)

  short8 a8, p8;
#define ALOAD(kk)                                          \
  do {                                                     \
    a8 = *(const short8*)&op0[abase + (kk)];               \
    p8 = *(const short8*)&op1[abase + (kk)];               \
  } while (0)

#define AWRITE(sb, kk)                                                                   \
  do {                                                                                   \
    const float inv = invt[((tid >> 2) << 3) | ((kk) >> 6)];                             \
    short8 pk;                                                                           \
    pk[0] = (short)f2b((b2f((unsigned short)a8[0]) + b2f((unsigned short)p8[0])) * inv); \
    pk[1] = (short)f2b((b2f((unsigned short)a8[1]) + b2f((unsigned short)p8[1])) * inv); \
    pk[2] = (short)f2b((b2f((unsigned short)a8[2]) + b2f((unsigned short)p8[2])) * inv); \
    pk[3] = (short)f2b((b2f((unsigned short)a8[3]) + b2f((unsigned short)p8[3])) * inv); \
    pk[4] = (short)f2b((b2f((unsigned short)a8[4]) + b2f((unsigned short)p8[4])) * inv); \
    pk[5] = (short)f2b((b2f((unsigned short)a8[5]) + b2f((unsigned short)p8[5])) * inv); \
    pk[6] = (short)f2b((b2f((unsigned short)a8[6]) + b2f((unsigned short)p8[6])) * inv); \
    pk[7] = (short)f2b((b2f((unsigned short)a8[7]) + b2f((unsigned short)p8[7])) * inv); \
    *(short8*)&ldsA[sb][(tid >> 2) * 32 + (tid & 3) * 8] = pk;                           \
  } while (0)

  ALOAD(0);
  BSTAGE(0, 0);
  __syncthreads();          // invt visible; drains A loads + B gll16
  AWRITE(0, 0);
  __syncthreads();          // A(0) visible

  for (int t = 0; t < 16; ++t) {
    const int cur = t & 1;
    const bool have = (t + 1 < 16);
    if (have) { ALOAD((t + 1) * 32); BSTAGE(cur ^ 1, (t + 1) * 32); }
    bf16x8 af[2], bfr[4];
#pragma unroll
    for (int i = 0; i < 2; ++i)
      af[i] = *(const bf16x8*)&ldsA[cur][(wm + i * 16 + l15) * 32 + lg * 8];
#pragma unroll
    for (int j = 0; j < 4; ++j)
      bfr[j] = *(const bf16x8*)&ldsB[cur][(wn + j * 16 + l15) * 32 + lg * 8];
    __builtin_amdgcn_s_setprio(1);
#pragma unroll
    for (int i = 0; i < 2; ++i)
#pragma unroll
      for (int j = 0; j < 4; ++j)
        acc[i][j] = MFMA16(af[i], bfr[j], acc[i][j]);
    __builtin_amdgcn_s_setprio(0);
    asm volatile("s_waitcnt vmcnt(0)" ::: "memory");
    __syncthreads();
    if (have) AWRITE(cur ^ 1, (t + 1) * 32);
    __syncthreads();
  }
#undef BSTAGE
#undef ALOAD
#undef AWRITE

#pragma unroll
  for (int i = 0; i < 2; ++i)
#pragma unroll
    for (int j = 0; j < 4; ++j)
#pragma unroll
      for (int r = 0; r < 4; ++r)
        C[(size_t)(m0 + wm + i * 16 + lg * 4 + r) * 512 + (n0 + wn + j * 16 + l15)] = acc[i][j][r];
}

extern "C" void kernel_launch(void* const* d_in, const int* in_sizes, int n_in,
                              void* d_out, int out_size, void* d_ws, size_t ws_size,
                              hipStream_t stream) {
  const float* x = (const float*)d_in[0];
  const float* cose = (const float*)d_in[1];
  const float* sine = (const float*)d_in[2];
  const int* mask = (const int*)d_in[3];
  const float* wq = (const float*)d_in[4];
  const float* wk = (const float*)d_in[5];
  const float* wv = (const float*)d_in[6];
  const float* wo = (const float*)d_in[7];
  float* out = (float*)d_out;
  char* ws = (char*)d_ws;

  // workspace layout (bytes)
  unsigned short* xb    = (unsigned short*)(ws);                 //  8,388,608  x bf16 [8192][512]
  unsigned short* wqkvT = (unsigned short*)(ws + 8388608);       //  1,572,864  [1536][512]
  unsigned short* woT   = (unsigned short*)(ws + 9961472);       //    524,288  [512][512]
  unsigned short* qbh   = (unsigned short*)(ws + 35651584);      //  8,388,608  roped q [B,H,S,HD]
  unsigned short* kbh   = (unsigned short*)(ws + 44040192);      //  8,388,608  roped k
  unsigned short* vtb   = (unsigned short*)(ws + 52428800);      //  8,388,608  V^T [B,H,HD,S]
  unsigned long long* mbits = (unsigned long long*)(ws + 60817408);  // 2,097,152
  unsigned short* op0 = (unsigned short*)(ws + 10485760);  // 8,388,608 bf16 partials (kh=0)
  unsigned short* op1 = (unsigned short*)(ws + 62914560);  // 8,388,608 bf16 partials (kh=1)
  float* ls0 = (float*)(ws + 79691776);   //    262,144
  float* ls1 = (float*)(ws + 79953920);   //    262,144  (ends 80,216,064)

  prep_kernel<<<6400, 256, 0, stream>>>(x, xb, mask, mbits, wq, wk, wv, wo, wqkvT, woT);
  gemm2<<<dim3(64, 12), 256, 0, stream>>>(xb, wqkvT, cose, sine, qbh, kbh, vtb);
  flash_kernel<<<512, 512, 0, stream>>>(qbh, kbh, vtb, mbits, op0, op1, ls0, ls1);
  gemm_fused<<<dim3(128, 4), 256, 0, stream>>>(op0, op1, ls0, ls1, woT, out);
}